// Round 1
// baseline (1311.431 us; speedup 1.0000x reference)
//
#include <hip/hip_runtime.h>
#include <hip/hip_bf16.h>
#include <cstdint>
#include <cstddef>

#define T_DIM 512
#define H_DIM 4096
#define I_DIM 11008
#define KSPLIT 4
// blocksize BS = 128

typedef __bf16 bf16_t;
typedef bf16_t bf16x8 __attribute__((ext_vector_type(8)));
typedef float f32x4 __attribute__((ext_vector_type(4)));
typedef unsigned short us16;
typedef us16 us16x8 __attribute__((ext_vector_type(8)));
typedef us16 us16x4 __attribute__((ext_vector_type(4)));

// fp32 -> bf16 RTNE (scalar)
__device__ __forceinline__ us16 f2bf(float f) {
    union { float f; uint32_t u; } v; v.f = f;
    uint32_t u = v.u;
    return (us16)((u + 0x7FFFu + ((u >> 16) & 1u)) >> 16);
}

// packed fp32x2 -> bf16x2 dword via HW v_cvt_pk_bf16_f32 (RTNE)
__device__ __forceinline__ uint32_t pkbf(float a, float b) {
    __hip_bfloat162 h = __float22bfloat162_rn(make_float2(a, b));
    uint32_t u;
    __builtin_memcpy(&u, &h, 4);
    return u;
}

__device__ __forceinline__ f32x4 mfma16(us16x8 a, us16x8 b, f32x4 c) {
    return __builtin_amdgcn_mfma_f32_16x16x32_bf16(
        __builtin_bit_cast(bf16x8, a), __builtin_bit_cast(bf16x8, b), c, 0, 0, 0);
}

// async global->LDS, 16B per lane (used by gemm2 only)
__device__ __forceinline__ void gload_lds16(const us16* g, us16* l) {
    __builtin_amdgcn_global_load_lds(
        (const __attribute__((address_space(1))) void*)g,
        (__attribute__((address_space(3))) void*)l, 16, 0, 0);
}

// ---------------------------------------------------------------- cvt_x
__global__ void cvt_x_kernel(const float* __restrict__ x, us16* __restrict__ xb) {
    int idx = (blockIdx.x * 256 + threadIdx.x) * 8;
    float4 a = *(const float4*)(x + idx);
    float4 b = *(const float4*)(x + idx + 4);
    us16x8 v;
    v[0] = f2bf(a.x); v[1] = f2bf(a.y); v[2] = f2bf(a.z); v[3] = f2bf(a.w);
    v[4] = f2bf(b.x); v[5] = f2bf(b.y); v[6] = f2bf(b.z); v[7] = f2bf(b.w);
    *(us16x8*)(xb + idx) = v;
}

// ---------------------------------------------------------------- trans_wd (no LDS)
// Wd [I][H] fp32 -> Wdt [H][I] bf16 dequant. Thread owns one i-row's 64B
// h-chunk (4x dwordx4, full line utilization); writes 16 lane-coalesced 2B
// stores (128B/wave-instr). Grid 43 x 256 = 11008 blocks.
__global__ __launch_bounds__(256) void trans_wd(
    const float* __restrict__ wd, const float* __restrict__ sd, us16* __restrict__ wdt)
{
    const int t   = threadIdx.x;
    const int bid = blockIdx.x;
    const int bi  = bid % (I_DIM / 256);      // 43
    const int bh  = bid / (I_DIM / 256);      // 256
    const int i   = bi * 256 + t;
    const int h0  = bh * 16;
    const float s = sd[(i >> 7) * (H_DIM / 128) + (h0 >> 7)];
    const float* src = wd + (size_t)i * H_DIM + h0;
    float4 v0 = *(const float4*)(src + 0);
    float4 v1 = *(const float4*)(src + 4);
    float4 v2 = *(const float4*)(src + 8);
    float4 v3 = *(const float4*)(src + 12);
    us16 o[16];
    o[0]=f2bf(v0.x*s); o[1]=f2bf(v0.y*s); o[2]=f2bf(v0.z*s); o[3]=f2bf(v0.w*s);
    o[4]=f2bf(v1.x*s); o[5]=f2bf(v1.y*s); o[6]=f2bf(v1.z*s); o[7]=f2bf(v1.w*s);
    o[8]=f2bf(v2.x*s); o[9]=f2bf(v2.y*s); o[10]=f2bf(v2.z*s); o[11]=f2bf(v2.w*s);
    o[12]=f2bf(v3.x*s); o[13]=f2bf(v3.y*s); o[14]=f2bf(v3.z*s); o[15]=f2bf(v3.w*s);
    #pragma unroll
    for (int j = 0; j < 16; ++j)
        wdt[(size_t)(h0 + j) * I_DIM + i] = o[j];
}

// ---------------------------------------------------------------- gemm1 (fused gate+up)
// BM=128 BN=64 BK=64, grid 688 = 8 XCD x 86.
// XCD swizzle: wgid = (bid%8)*86 + bid/8 puts the 4 bm-blocks of each bn
// temporally adjacent on ONE XCD -> B weight panel fetched ~once into that
// XCD's L2 (was 4 fetches across 4 XCDs; FETCH 738 MB -> ~430 MB predicted).
// Depth-2 register prefetch (two named sets, loop unrolled x2): loads issued
// 2 MFMA phases before their vmcnt wait -> covers L3/HBM latency.
__global__ __launch_bounds__(256, 3) void gemm1_fused(
    const us16*  __restrict__ xb,
    const float* __restrict__ wg,
    const float* __restrict__ wu,
    const float* __restrict__ sgArr,
    const float* __restrict__ suArr,
    us16*        __restrict__ hbuf)
{
    __shared__ us16 As [128 * 72];    // stride 72: 16B-aligned, conflict-free frag reads
    __shared__ us16 Bgs[64 * 72];
    __shared__ us16 Bus[64 * 72];

    const int t    = threadIdx.x;
    const int bid  = blockIdx.x;              // 688 = 8 * 86
    const int wgid = (bid & 7) * 86 + (bid >> 3);   // XCD-contiguous
    const int bm   = wgid & 3;
    const int bn   = wgid >> 2;               // 0..171
    const int m0   = bm * 128, n0 = bn * 64;

    const int w = t >> 6, l = t & 63;
    const int q = l >> 4, r = l & 15;
    const int m_off = (w >> 1) * 64, n_off = (w & 1) * 32;

    // staging coordinates (fixed per thread)
    const int ar[4] = { t >> 3, (t + 256) >> 3, (t + 512) >> 3, (t + 768) >> 3 };
    const int ac    = (t & 7) * 8;                 // A: col in elems
    const int br[4] = { t >> 4, (t + 256) >> 4, (t + 512) >> 4, (t + 768) >> 4 };
    const int bc    = (t & 15) * 4;                // B: col in floats

    const int sRow  = (bn >> 1) * (H_DIM / 128);

    f32x4 accg[4][2], accu[4][2];
    #pragma unroll
    for (int m = 0; m < 4; ++m)
        #pragma unroll
        for (int n = 0; n < 2; ++n) {
            accg[m][n] = f32x4{0.f,0.f,0.f,0.f};
            accu[m][n] = f32x4{0.f,0.f,0.f,0.f};
        }

    // two prefetch sets (depth 2)
    us16x8 ab0[4], ab1[4];
    float4 gb0[4], ub0[4], gb1[4], ub1[4];

    // prologue: prefetch kt=0 (set0) and kt=1 (set1)
    #pragma unroll
    for (int p = 0; p < 4; ++p) {
        ab0[p] = *(const us16x8*)(xb + (size_t)(m0 + ar[p]) * H_DIM + 0  + ac);
        ab1[p] = *(const us16x8*)(xb + (size_t)(m0 + ar[p]) * H_DIM + 64 + ac);
    }
    #pragma unroll
    for (int p = 0; p < 4; ++p) {
        gb0[p] = *(const float4*)(wg + (size_t)(n0 + br[p]) * H_DIM + 0  + bc);
        ub0[p] = *(const float4*)(wu + (size_t)(n0 + br[p]) * H_DIM + 0  + bc);
        gb1[p] = *(const float4*)(wg + (size_t)(n0 + br[p]) * H_DIM + 64 + bc);
        ub1[p] = *(const float4*)(wu + (size_t)(n0 + br[p]) * H_DIM + 64 + bc);
    }

    // scale rotation: scales for pair ki loaded one unrolled-iter ahead
    float sg_c = sgArr[sRow];
    float su_c = suArr[sRow];

    for (int kt = 0; kt < H_DIM / 64; kt += 2) {   // 32 unrolled iters (64 k-steps)
        const int ki = kt >> 1;                    // scale pair index, shared by kt, kt+1
        const float sg = sg_c, su = su_c;
        {
            const int kn = (ki + 1) & 31;          // wraps harmlessly on last iter
            sg_c = sgArr[sRow + kn];
            su_c = suArr[sRow + kn];
        }

        // ================= sub-iter 0: data for k-step kt (set0) =================
        __builtin_amdgcn_s_barrier();              // LDS WAR (reads of prev step done)

        #pragma unroll
        for (int p = 0; p < 4; ++p)
            *(us16x8*)(As + ar[p] * 72 + ac) = ab0[p];
        #pragma unroll
        for (int p = 0; p < 4; ++p) {
            uint2 vg, vu;
            vg.x = pkbf(gb0[p].x * sg, gb0[p].y * sg);
            vg.y = pkbf(gb0[p].z * sg, gb0[p].w * sg);
            vu.x = pkbf(ub0[p].x * su, ub0[p].y * su);
            vu.y = pkbf(ub0[p].z * su, ub0[p].w * su);
            *(uint2*)(Bgs + br[p] * 72 + bc) = vg;
            *(uint2*)(Bus + br[p] * 72 + bc) = vu;
        }

        // refill set0 with k-step kt+2 (wrap: last refill redundant, keeps counts uniform)
        {
            const int kn = ((kt + 2) & 63) * 64;
            #pragma unroll
            for (int p = 0; p < 4; ++p)
                ab0[p] = *(const us16x8*)(xb + (size_t)(m0 + ar[p]) * H_DIM + kn + ac);
            #pragma unroll
            for (int p = 0; p < 4; ++p) {
                gb0[p] = *(const float4*)(wg + (size_t)(n0 + br[p]) * H_DIM + kn + bc);
                ub0[p] = *(const float4*)(wu + (size_t)(n0 + br[p]) * H_DIM + kn + bc);
            }
        }

        // pre-MFMA barrier WITHOUT vmcnt drain: prefetches stay in flight
        __builtin_amdgcn_s_waitcnt(0xC07F);        // lgkmcnt(0) only
        __builtin_amdgcn_s_barrier();

        #pragma unroll
        for (int ks = 0; ks < 2; ++ks) {
            us16x8 af[4], bg[2], bu[2];
            #pragma unroll
            for (int m = 0; m < 4; ++m)
                af[m] = *(const us16x8*)(As + (m_off + m * 16 + r) * 72 + ks * 32 + q * 8);
            #pragma unroll
            for (int n = 0; n < 2; ++n) {
                bg[n] = *(const us16x8*)(Bgs + (n_off + n * 16 + r) * 72 + ks * 32 + q * 8);
                bu[n] = *(const us16x8*)(Bus + (n_off + n * 16 + r) * 72 + ks * 32 + q * 8);
            }
            #pragma unroll
            for (int m = 0; m < 4; ++m)
                #pragma unroll
                for (int n = 0; n < 2; ++n) {
                    accg[m][n] = mfma16(af[m], bg[n], accg[m][n]);
                    accu[m][n] = mfma16(af[m], bu[n], accu[m][n]);
                }
        }

        // ================= sub-iter 1: data for k-step kt+1 (set1) =================
        __builtin_amdgcn_s_barrier();

        #pragma unroll
        for (int p = 0; p < 4; ++p)
            *(us16x8*)(As + ar[p] * 72 + ac) = ab1[p];
        #pragma unroll
        for (int p = 0; p < 4; ++p) {
            uint2 vg, vu;
            vg.x = pkbf(gb1[p].x * sg, gb1[p].y * sg);
            vg.y = pkbf(gb1[p].z * sg, gb1[p].w * sg);
            vu.x = pkbf(ub1[p].x * su, ub1[p].y * su);
            vu.y = pkbf(ub1[p].z * su, ub1[p].w * su);
            *(uint2*)(Bgs + br[p] * 72 + bc) = vg;
            *(uint2*)(Bus + br[p] * 72 + bc) = vu;
        }

        // refill set1 with k-step kt+3
        {
            const int kn = ((kt + 3) & 63) * 64;
            #pragma unroll
            for (int p = 0; p < 4; ++p)
                ab1[p] = *(const us16x8*)(xb + (size_t)(m0 + ar[p]) * H_DIM + kn + ac);
            #pragma unroll
            for (int p = 0; p < 4; ++p) {
                gb1[p] = *(const float4*)(wg + (size_t)(n0 + br[p]) * H_DIM + kn + bc);
                ub1[p] = *(const float4*)(wu + (size_t)(n0 + br[p]) * H_DIM + kn + bc);
            }
        }

        __builtin_amdgcn_s_waitcnt(0xC07F);        // lgkmcnt(0) only
        __builtin_amdgcn_s_barrier();

        #pragma unroll
        for (int ks = 0; ks < 2; ++ks) {
            us16x8 af[4], bg[2], bu[2];
            #pragma unroll
            for (int m = 0; m < 4; ++m)
                af[m] = *(const us16x8*)(As + (m_off + m * 16 + r) * 72 + ks * 32 + q * 8);
            #pragma unroll
            for (int n = 0; n < 2; ++n) {
                bg[n] = *(const us16x8*)(Bgs + (n_off + n * 16 + r) * 72 + ks * 32 + q * 8);
                bu[n] = *(const us16x8*)(Bus + (n_off + n * 16 + r) * 72 + ks * 32 + q * 8);
            }
            #pragma unroll
            for (int m = 0; m < 4; ++m)
                #pragma unroll
                for (int n = 0; n < 2; ++n) {
                    accg[m][n] = mfma16(af[m], bg[n], accg[m][n]);
                    accu[m][n] = mfma16(af[m], bu[n], accu[m][n]);
                }
        }
    }

    #pragma unroll
    for (int m = 0; m < 4; ++m)
        #pragma unroll
        for (int n = 0; n < 2; ++n)
            #pragma unroll
            for (int rr = 0; rr < 4; ++rr) {
                int grow = m0 + m_off + m * 16 + q * 4 + rr;
                int gcol = n0 + n_off + n * 16 + r;
                float g = accg[m][n][rr];
                float u = accu[m][n][rr];
                float hv = (g / (1.0f + __expf(-g))) * u;
                hbuf[(size_t)grow * I_DIM + gcol] = f2bf(hv);
            }
}

// ---------------------------------------------------------------- gemm2 split-K
// 128x128 tile, KSPLIT=4 -> 512 blocks = 2/CU. Both operands bf16 K-contig
// via global_load_lds. XCD swizzle: 512 = 8 XCD x 64; decompose so the 4
// bm-blocks of each (bn,bk) are consecutive on ONE XCD (wdt panel fetched
// once per XCD instead of 4x across XCDs); each XCD carries a single bk with
// 16 bn values -> its 4 hb slices (2.8 MB) also get L2 reuse.
template <bool USE_PART>
__global__ __launch_bounds__(256, 2) void gemm2_splitk(
    const us16* __restrict__ hbuf,   // [T][I]
    const us16* __restrict__ wdt,    // [H][I]
    float*      __restrict__ outp)   // partials [KSPLIT][T][H] or out [T][H]
{
    __shared__ us16 As[128 * 32];
    __shared__ us16 Bs[128 * 32];

    const int t   = threadIdx.x;
    const int bid = blockIdx.x;          // 512 = 8 * 64
    const int x   = bid & 7;             // XCD
    const int j   = bid >> 3;            // 0..63 within XCD
    const int bm  = j & 3;
    const int g   = x * 16 + (j >> 2);   // 0..127
    const int bn  = g & 31;
    const int bk  = g >> 5;
    const int m0  = bm * 128, n0 = bn * 128;
    const int kbase = bk * (I_DIM / KSPLIT);

    const int w = t >> 6, l = t & 63;
    const int q = l >> 4, r = l & 15;
    const int m_off = (w >> 1) * 64, n_off = (w & 1) * 64;

    const int arow = w * 16 + (l >> 2);
    const int acol = (l & 3) * 8;

    f32x4 acc[4][4];
    #pragma unroll
    for (int m = 0; m < 4; ++m)
        #pragma unroll
        for (int n = 0; n < 4; ++n) acc[m][n] = f32x4{0.f,0.f,0.f,0.f};

    for (int kt = 0; kt < (I_DIM / KSPLIT) / 32; ++kt) {   // 86
        const int k0 = kbase + kt * 32;
        #pragma unroll
        for (int p = 0; p < 2; ++p) {
            gload_lds16(hbuf + (size_t)(m0 + p * 64 + arow) * I_DIM + k0 + acol,
                        As + (p * 64 + w * 16) * 32);
            gload_lds16(wdt + (size_t)(n0 + p * 64 + arow) * I_DIM + k0 + acol,
                        Bs + (p * 64 + w * 16) * 32);
        }
        __syncthreads();

        us16x8 af[4], bfr[4];
        #pragma unroll
        for (int m = 0; m < 4; ++m)
            af[m] = *(const us16x8*)(As + (m_off + m * 16 + r) * 32 + q * 8);
        #pragma unroll
        for (int n = 0; n < 4; ++n)
            bfr[n] = *(const us16x8*)(Bs + (n_off + n * 16 + r) * 32 + q * 8);
        #pragma unroll
        for (int m = 0; m < 4; ++m)
            #pragma unroll
            for (int n = 0; n < 4; ++n)
                acc[m][n] = mfma16(af[m], bfr[n], acc[m][n]);
        __syncthreads();
    }

    float* base = USE_PART ? outp + (size_t)bk * T_DIM * H_DIM : outp;
    #pragma unroll
    for (int m = 0; m < 4; ++m)
        #pragma unroll
        for (int n = 0; n < 4; ++n)
            #pragma unroll
            for (int rr = 0; rr < 4; ++rr) {
                int grow = m0 + m_off + m * 16 + q * 4 + rr;
                int gcol = n0 + n_off + n * 16 + r;
                if (USE_PART)
                    base[(size_t)grow * H_DIM + gcol] = acc[m][n][rr];
                else
                    atomicAdd(&base[(size_t)grow * H_DIM + gcol], acc[m][n][rr]);
            }
}

// ---------------------------------------------------------------- reduce partials
__global__ void reduce4_kernel(const float* __restrict__ part, float* __restrict__ out) {
    const size_t i = ((size_t)blockIdx.x * 256 + threadIdx.x) * 4;
    const size_t S = (size_t)T_DIM * H_DIM;
    float4 a = *(const float4*)(part + i);
    float4 b = *(const float4*)(part + S + i);
    float4 c = *(const float4*)(part + 2 * S + i);
    float4 d = *(const float4*)(part + 3 * S + i);
    float4 o;
    o.x = a.x + b.x + c.x + d.x;
    o.y = a.y + b.y + c.y + d.y;
    o.z = a.z + b.z + c.z + d.z;
    o.w = a.w + b.w + c.w + d.w;
    *(float4*)(out + i) = o;
}

// ---------------------------------------------------------------- launch
extern "C" void kernel_launch(void* const* d_in, const int* in_sizes, int n_in,
                              void* d_out, int out_size, void* d_ws, size_t ws_size,
                              hipStream_t stream) {
    const float* x  = (const float*)d_in[0];
    const float* wg = (const float*)d_in[1];
    const float* wu = (const float*)d_in[2];
    const float* wd = (const float*)d_in[3];
    const float* sg = (const float*)d_in[4];
    const float* su = (const float*)d_in[5];
    const float* sd = (const float*)d_in[6];
    float* out = (float*)d_out;

    const size_t xb_bytes   = (size_t)T_DIM * H_DIM * 2;           //  4.0 MB
    const size_t hb_bytes   = (size_t)T_DIM * I_DIM * 2;           // 11.3 MB
    const size_t wdt_bytes  = (size_t)H_DIM * I_DIM * 2;           // 90.2 MB
    const size_t part_bytes = (size_t)KSPLIT * T_DIM * H_DIM * 4;  // 33.6 MB

    us16*  xb   = (us16*)d_ws;
    us16*  hb   = (us16*)((char*)d_ws + xb_bytes);
    us16*  wdt  = (us16*)((char*)d_ws + xb_bytes + hb_bytes);
    float* part = (float*)((char*)d_ws + xb_bytes + hb_bytes + wdt_bytes);

    cvt_x_kernel<<<(T_DIM * H_DIM) / (256 * 8), 256, 0, stream>>>(x, xb);
    gemm1_fused<<<(I_DIM / 64) * (T_DIM / 128), 256, 0, stream>>>(xb, wg, wu, sg, su, hb);
    trans_wd<<<(I_DIM / 256) * (H_DIM / 16), 256, 0, stream>>>(wd, sd, wdt);

    if (ws_size >= xb_bytes + hb_bytes + wdt_bytes + part_bytes) {
        gemm2_splitk<true><<<(T_DIM / 128) * (H_DIM / 128) * KSPLIT, 256, 0, stream>>>(hb, wdt, part);
        reduce4_kernel<<<(T_DIM * H_DIM) / (256 * 4), 256, 0, stream>>>(part, out);
    } else {
        (void)hipMemsetAsync(out, 0, (size_t)T_DIM * H_DIM * sizeof(float), stream);
        gemm2_splitk<false><<<(T_DIM / 128) * (H_DIM / 128) * KSPLIT, 256, 0, stream>>>(hb, wdt, out);
    }
}

// Round 2
// 666.306 us; speedup vs baseline: 1.9682x; 1.9682x over previous
//
#include <hip/hip_runtime.h>
#include <hip/hip_bf16.h>
#include <cstdint>
#include <cstddef>

#define T_DIM 512
#define H_DIM 4096
#define I_DIM 11008
#define KSPLIT 4
// blocksize BS = 128

typedef __bf16 bf16_t;
typedef bf16_t bf16x8 __attribute__((ext_vector_type(8)));
typedef float f32x4 __attribute__((ext_vector_type(4)));
typedef unsigned short us16;
typedef us16 us16x8 __attribute__((ext_vector_type(8)));
typedef us16 us16x4 __attribute__((ext_vector_type(4)));

// fp32 -> bf16 RTNE (scalar)
__device__ __forceinline__ us16 f2bf(float f) {
    union { float f; uint32_t u; } v; v.f = f;
    uint32_t u = v.u;
    return (us16)((u + 0x7FFFu + ((u >> 16) & 1u)) >> 16);
}

// packed fp32x2 -> bf16x2 dword via HW v_cvt_pk_bf16_f32 (RTNE)
__device__ __forceinline__ uint32_t pkbf(float a, float b) {
    __hip_bfloat162 h = __float22bfloat162_rn(make_float2(a, b));
    uint32_t u;
    __builtin_memcpy(&u, &h, 4);
    return u;
}

__device__ __forceinline__ f32x4 mfma16(us16x8 a, us16x8 b, f32x4 c) {
    return __builtin_amdgcn_mfma_f32_16x16x32_bf16(
        __builtin_bit_cast(bf16x8, a), __builtin_bit_cast(bf16x8, b), c, 0, 0, 0);
}

// async global->LDS, 16B per lane (used by gemm2 only)
__device__ __forceinline__ void gload_lds16(const us16* g, us16* l) {
    __builtin_amdgcn_global_load_lds(
        (const __attribute__((address_space(1))) void*)g,
        (__attribute__((address_space(3))) void*)l, 16, 0, 0);
}

// ---------------------------------------------------------------- cvt_x
__global__ void cvt_x_kernel(const float* __restrict__ x, us16* __restrict__ xb) {
    int idx = (blockIdx.x * 256 + threadIdx.x) * 8;
    float4 a = *(const float4*)(x + idx);
    float4 b = *(const float4*)(x + idx + 4);
    us16x8 v;
    v[0] = f2bf(a.x); v[1] = f2bf(a.y); v[2] = f2bf(a.z); v[3] = f2bf(a.w);
    v[4] = f2bf(b.x); v[5] = f2bf(b.y); v[6] = f2bf(b.z); v[7] = f2bf(b.w);
    *(us16x8*)(xb + idx) = v;
}

// ---------------------------------------------------------------- trans_wd (no LDS)
// Wd [I][H] fp32 -> Wdt [H][I] bf16 dequant. Thread owns one i-row's 64B
// h-chunk (4x dwordx4, full line utilization); writes 16 lane-coalesced 2B
// stores (128B/wave-instr). Grid 43 x 256 = 11008 blocks.
__global__ __launch_bounds__(256) void trans_wd(
    const float* __restrict__ wd, const float* __restrict__ sd, us16* __restrict__ wdt)
{
    const int t   = threadIdx.x;
    const int bid = blockIdx.x;
    const int bi  = bid % (I_DIM / 256);      // 43
    const int bh  = bid / (I_DIM / 256);      // 256
    const int i   = bi * 256 + t;
    const int h0  = bh * 16;
    const float s = sd[(i >> 7) * (H_DIM / 128) + (h0 >> 7)];
    const float* src = wd + (size_t)i * H_DIM + h0;
    float4 v0 = *(const float4*)(src + 0);
    float4 v1 = *(const float4*)(src + 4);
    float4 v2 = *(const float4*)(src + 8);
    float4 v3 = *(const float4*)(src + 12);
    us16 o[16];
    o[0]=f2bf(v0.x*s); o[1]=f2bf(v0.y*s); o[2]=f2bf(v0.z*s); o[3]=f2bf(v0.w*s);
    o[4]=f2bf(v1.x*s); o[5]=f2bf(v1.y*s); o[6]=f2bf(v1.z*s); o[7]=f2bf(v1.w*s);
    o[8]=f2bf(v2.x*s); o[9]=f2bf(v2.y*s); o[10]=f2bf(v2.z*s); o[11]=f2bf(v2.w*s);
    o[12]=f2bf(v3.x*s); o[13]=f2bf(v3.y*s); o[14]=f2bf(v3.z*s); o[15]=f2bf(v3.w*s);
    #pragma unroll
    for (int j = 0; j < 16; ++j)
        wdt[(size_t)(h0 + j) * I_DIM + i] = o[j];
}

// ---------------------------------------------------------------- gemm1 (fused gate+up)
// BM=128 BN=64 BK=64, grid 688 = 8 XCD x 86. Depth-1 register prefetch
// (depth-2 spilled: R1 showed WRITE_SIZE 14MB->1.46GB scratch traffic).
// XCD swizzle: wgid = (bid%8)*86 + bid/8 puts the 4 bm-blocks of each bn
// temporally adjacent on ONE XCD -> B weight panel fetched ~once into that
// XCD's L2 (was 4 fetches spread across 4 XCDs).
__global__ __launch_bounds__(256, 3) void gemm1_fused(
    const us16*  __restrict__ xb,
    const float* __restrict__ wg,
    const float* __restrict__ wu,
    const float* __restrict__ sgArr,
    const float* __restrict__ suArr,
    us16*        __restrict__ hbuf)
{
    __shared__ us16 As [128 * 72];    // stride 72: 16B-aligned, conflict-free frag reads
    __shared__ us16 Bgs[64 * 72];
    __shared__ us16 Bus[64 * 72];

    const int t    = threadIdx.x;
    const int bid  = blockIdx.x;              // 688 = 8 * 86
    const int wgid = (bid & 7) * 86 + (bid >> 3);   // XCD-contiguous
    const int bm   = wgid & 3;
    const int bn   = wgid >> 2;               // 0..171
    const int m0   = bm * 128, n0 = bn * 64;

    const int w = t >> 6, l = t & 63;
    const int q = l >> 4, r = l & 15;
    const int m_off = (w >> 1) * 64, n_off = (w & 1) * 32;

    // staging coordinates (fixed per thread)
    const int ar[4] = { t >> 3, (t + 256) >> 3, (t + 512) >> 3, (t + 768) >> 3 };
    const int ac    = (t & 7) * 8;                 // A: col in elems
    const int br[4] = { t >> 4, (t + 256) >> 4, (t + 512) >> 4, (t + 768) >> 4 };
    const int bc    = (t & 15) * 4;                // B: col in floats

    f32x4 accg[4][2], accu[4][2];
    #pragma unroll
    for (int m = 0; m < 4; ++m)
        #pragma unroll
        for (int n = 0; n < 2; ++n) {
            accg[m][n] = f32x4{0.f,0.f,0.f,0.f};
            accu[m][n] = f32x4{0.f,0.f,0.f,0.f};
        }

    us16x8 ab[4];
    float4 gb[4], ub[4];

    // prologue: prefetch iter 0
    {
        const int k0 = 0;
        #pragma unroll
        for (int p = 0; p < 4; ++p)
            ab[p] = *(const us16x8*)(xb + (size_t)(m0 + ar[p]) * H_DIM + k0 + ac);
        #pragma unroll
        for (int p = 0; p < 4; ++p) {
            gb[p] = *(const float4*)(wg + (size_t)(n0 + br[p]) * H_DIM + k0 + bc);
            ub[p] = *(const float4*)(wu + (size_t)(n0 + br[p]) * H_DIM + k0 + bc);
        }
    }

    for (int kt = 0; kt < H_DIM / 64; ++kt) {      // 64 iters
        const float sg = sgArr[(bn >> 1) * (H_DIM / 128) + (kt >> 1)];
        const float su = suArr[(bn >> 1) * (H_DIM / 128) + (kt >> 1)];

        __builtin_amdgcn_s_barrier();              // LDS WAR (reads of kt-1 done)

        // consume prefetched regs -> LDS
        #pragma unroll
        for (int p = 0; p < 4; ++p)
            *(us16x8*)(As + ar[p] * 72 + ac) = ab[p];
        #pragma unroll
        for (int p = 0; p < 4; ++p) {
            uint2 vg, vu;
            vg.x = pkbf(gb[p].x * sg, gb[p].y * sg);
            vg.y = pkbf(gb[p].z * sg, gb[p].w * sg);
            vu.x = pkbf(ub[p].x * su, ub[p].y * su);
            vu.y = pkbf(ub[p].z * su, ub[p].w * su);
            *(uint2*)(Bgs + br[p] * 72 + bc) = vg;
            *(uint2*)(Bus + br[p] * 72 + bc) = vu;
        }

        // prefetch next iter (wrap: last prefetch redundant but keeps counts uniform)
        {
            const int kn = ((kt + 1) & 63) * 64;
            #pragma unroll
            for (int p = 0; p < 4; ++p)
                ab[p] = *(const us16x8*)(xb + (size_t)(m0 + ar[p]) * H_DIM + kn + ac);
            #pragma unroll
            for (int p = 0; p < 4; ++p) {
                gb[p] = *(const float4*)(wg + (size_t)(n0 + br[p]) * H_DIM + kn + bc);
                ub[p] = *(const float4*)(wu + (size_t)(n0 + br[p]) * H_DIM + kn + bc);
            }
        }

        // pre-MFMA barrier WITHOUT vmcnt drain: prefetch stays in flight
        __builtin_amdgcn_s_waitcnt(0xC07F);        // lgkmcnt(0) only
        __builtin_amdgcn_s_barrier();

        #pragma unroll
        for (int ks = 0; ks < 2; ++ks) {
            us16x8 af[4], bg[2], bu[2];
            #pragma unroll
            for (int m = 0; m < 4; ++m)
                af[m] = *(const us16x8*)(As + (m_off + m * 16 + r) * 72 + ks * 32 + q * 8);
            #pragma unroll
            for (int n = 0; n < 2; ++n) {
                bg[n] = *(const us16x8*)(Bgs + (n_off + n * 16 + r) * 72 + ks * 32 + q * 8);
                bu[n] = *(const us16x8*)(Bus + (n_off + n * 16 + r) * 72 + ks * 32 + q * 8);
            }
            #pragma unroll
            for (int m = 0; m < 4; ++m)
                #pragma unroll
                for (int n = 0; n < 2; ++n) {
                    accg[m][n] = mfma16(af[m], bg[n], accg[m][n]);
                    accu[m][n] = mfma16(af[m], bu[n], accu[m][n]);
                }
        }
    }

    #pragma unroll
    for (int m = 0; m < 4; ++m)
        #pragma unroll
        for (int n = 0; n < 2; ++n)
            #pragma unroll
            for (int rr = 0; rr < 4; ++rr) {
                int grow = m0 + m_off + m * 16 + q * 4 + rr;
                int gcol = n0 + n_off + n * 16 + r;
                float g = accg[m][n][rr];
                float u = accu[m][n][rr];
                float hv = (g / (1.0f + __expf(-g))) * u;
                hbuf[(size_t)grow * I_DIM + gcol] = f2bf(hv);
            }
}

// ---------------------------------------------------------------- gemm2 split-K
// 128x128 tile, KSPLIT=4 -> 512 blocks = 2/CU. Both operands bf16 K-contig
// via global_load_lds. XCD swizzle: 512 = 8 XCD x 64; the 4 bm-blocks of
// each (bn,bk) are consecutive on ONE XCD (wdt panel fetched once per XCD
// instead of 4x across XCDs); each XCD carries a single bk with 16 bn
// values -> its hb slices also get L2 reuse.
template <bool USE_PART>
__global__ __launch_bounds__(256, 2) void gemm2_splitk(
    const us16* __restrict__ hbuf,   // [T][I]
    const us16* __restrict__ wdt,    // [H][I]
    float*      __restrict__ outp)   // partials [KSPLIT][T][H] or out [T][H]
{
    __shared__ us16 As[128 * 32];
    __shared__ us16 Bs[128 * 32];

    const int t   = threadIdx.x;
    const int bid = blockIdx.x;          // 512 = 8 * 64
    const int x   = bid & 7;             // XCD
    const int j   = bid >> 3;            // 0..63 within XCD
    const int bm  = j & 3;
    const int g   = x * 16 + (j >> 2);   // 0..127
    const int bn  = g & 31;
    const int bk  = g >> 5;
    const int m0  = bm * 128, n0 = bn * 128;
    const int kbase = bk * (I_DIM / KSPLIT);

    const int w = t >> 6, l = t & 63;
    const int q = l >> 4, r = l & 15;
    const int m_off = (w >> 1) * 64, n_off = (w & 1) * 64;

    const int arow = w * 16 + (l >> 2);
    const int acol = (l & 3) * 8;

    f32x4 acc[4][4];
    #pragma unroll
    for (int m = 0; m < 4; ++m)
        #pragma unroll
        for (int n = 0; n < 4; ++n) acc[m][n] = f32x4{0.f,0.f,0.f,0.f};

    for (int kt = 0; kt < (I_DIM / KSPLIT) / 32; ++kt) {   // 86
        const int k0 = kbase + kt * 32;
        #pragma unroll
        for (int p = 0; p < 2; ++p) {
            gload_lds16(hbuf + (size_t)(m0 + p * 64 + arow) * I_DIM + k0 + acol,
                        As + (p * 64 + w * 16) * 32);
            gload_lds16(wdt + (size_t)(n0 + p * 64 + arow) * I_DIM + k0 + acol,
                        Bs + (p * 64 + w * 16) * 32);
        }
        __syncthreads();

        us16x8 af[4], bfr[4];
        #pragma unroll
        for (int m = 0; m < 4; ++m)
            af[m] = *(const us16x8*)(As + (m_off + m * 16 + r) * 32 + q * 8);
        #pragma unroll
        for (int n = 0; n < 4; ++n)
            bfr[n] = *(const us16x8*)(Bs + (n_off + n * 16 + r) * 32 + q * 8);
        #pragma unroll
        for (int m = 0; m < 4; ++m)
            #pragma unroll
            for (int n = 0; n < 4; ++n)
                acc[m][n] = mfma16(af[m], bfr[n], acc[m][n]);
        __syncthreads();
    }

    float* base = USE_PART ? outp + (size_t)bk * T_DIM * H_DIM : outp;
    #pragma unroll
    for (int m = 0; m < 4; ++m)
        #pragma unroll
        for (int n = 0; n < 4; ++n)
            #pragma unroll
            for (int rr = 0; rr < 4; ++rr) {
                int grow = m0 + m_off + m * 16 + q * 4 + rr;
                int gcol = n0 + n_off + n * 16 + r;
                if (USE_PART)
                    base[(size_t)grow * H_DIM + gcol] = acc[m][n][rr];
                else
                    atomicAdd(&base[(size_t)grow * H_DIM + gcol], acc[m][n][rr]);
            }
}

// ---------------------------------------------------------------- reduce partials
__global__ void reduce4_kernel(const float* __restrict__ part, float* __restrict__ out) {
    const size_t i = ((size_t)blockIdx.x * 256 + threadIdx.x) * 4;
    const size_t S = (size_t)T_DIM * H_DIM;
    float4 a = *(const float4*)(part + i);
    float4 b = *(const float4*)(part + S + i);
    float4 c = *(const float4*)(part + 2 * S + i);
    float4 d = *(const float4*)(part + 3 * S + i);
    float4 o;
    o.x = a.x + b.x + c.x + d.x;
    o.y = a.y + b.y + c.y + d.y;
    o.z = a.z + b.z + c.z + d.z;
    o.w = a.w + b.w + c.w + d.w;
    *(float4*)(out + i) = o;
}

// ---------------------------------------------------------------- launch
extern "C" void kernel_launch(void* const* d_in, const int* in_sizes, int n_in,
                              void* d_out, int out_size, void* d_ws, size_t ws_size,
                              hipStream_t stream) {
    const float* x  = (const float*)d_in[0];
    const float* wg = (const float*)d_in[1];
    const float* wu = (const float*)d_in[2];
    const float* wd = (const float*)d_in[3];
    const float* sg = (const float*)d_in[4];
    const float* su = (const float*)d_in[5];
    const float* sd = (const float*)d_in[6];
    float* out = (float*)d_out;

    const size_t xb_bytes   = (size_t)T_DIM * H_DIM * 2;           //  4.0 MB
    const size_t hb_bytes   = (size_t)T_DIM * I_DIM * 2;           // 11.3 MB
    const size_t wdt_bytes  = (size_t)H_DIM * I_DIM * 2;           // 90.2 MB
    const size_t part_bytes = (size_t)KSPLIT * T_DIM * H_DIM * 4;  // 33.6 MB

    us16*  xb   = (us16*)d_ws;
    us16*  hb   = (us16*)((char*)d_ws + xb_bytes);
    us16*  wdt  = (us16*)((char*)d_ws + xb_bytes + hb_bytes);
    float* part = (float*)((char*)d_ws + xb_bytes + hb_bytes + wdt_bytes);

    cvt_x_kernel<<<(T_DIM * H_DIM) / (256 * 8), 256, 0, stream>>>(x, xb);
    gemm1_fused<<<(I_DIM / 64) * (T_DIM / 128), 256, 0, stream>>>(xb, wg, wu, sg, su, hb);
    trans_wd<<<(I_DIM / 256) * (H_DIM / 16), 256, 0, stream>>>(wd, sd, wdt);

    if (ws_size >= xb_bytes + hb_bytes + wdt_bytes + part_bytes) {
        gemm2_splitk<true><<<(T_DIM / 128) * (H_DIM / 128) * KSPLIT, 256, 0, stream>>>(hb, wdt, part);
        reduce4_kernel<<<(T_DIM * H_DIM) / (256 * 4), 256, 0, stream>>>(part, out);
    } else {
        (void)hipMemsetAsync(out, 0, (size_t)T_DIM * H_DIM * sizeof(float), stream);
        gemm2_splitk<false><<<(T_DIM / 128) * (H_DIM / 128) * KSPLIT, 256, 0, stream>>>(hb, wdt, out);
    }
}

// Round 4
// 643.442 us; speedup vs baseline: 2.0381x; 1.0355x over previous
//
#include <hip/hip_runtime.h>
#include <hip/hip_bf16.h>
#include <cstdint>
#include <cstddef>

#define T_DIM 512
#define H_DIM 4096
#define I_DIM 11008
#define KSPLIT 4
// blocksize BS = 128

typedef __bf16 bf16_t;
typedef bf16_t bf16x8 __attribute__((ext_vector_type(8)));
typedef float f32x4 __attribute__((ext_vector_type(4)));
typedef unsigned short us16;
typedef us16 us16x8 __attribute__((ext_vector_type(8)));
typedef us16 us16x4 __attribute__((ext_vector_type(4)));

// fp32 -> bf16 RTNE (scalar)
__device__ __forceinline__ us16 f2bf(float f) {
    union { float f; uint32_t u; } v; v.f = f;
    uint32_t u = v.u;
    return (us16)((u + 0x7FFFu + ((u >> 16) & 1u)) >> 16);
}

// packed fp32x2 -> bf16x2 dword via HW v_cvt_pk_bf16_f32 (RTNE)
__device__ __forceinline__ uint32_t pkbf(float a, float b) {
    __hip_bfloat162 h = __float22bfloat162_rn(make_float2(a, b));
    uint32_t u;
    __builtin_memcpy(&u, &h, 4);
    return u;
}

__device__ __forceinline__ f32x4 mfma16(us16x8 a, us16x8 b, f32x4 c) {
    return __builtin_amdgcn_mfma_f32_16x16x32_bf16(
        __builtin_bit_cast(bf16x8, a), __builtin_bit_cast(bf16x8, b), c, 0, 0, 0);
}

// ---------------------------------------------------------------- cvt_x
__global__ void cvt_x_kernel(const float* __restrict__ x, us16* __restrict__ xb) {
    int idx = (blockIdx.x * 256 + threadIdx.x) * 8;
    float4 a = *(const float4*)(x + idx);
    float4 b = *(const float4*)(x + idx + 4);
    us16x8 v;
    v[0] = f2bf(a.x); v[1] = f2bf(a.y); v[2] = f2bf(a.z); v[3] = f2bf(a.w);
    v[4] = f2bf(b.x); v[5] = f2bf(b.y); v[6] = f2bf(b.z); v[7] = f2bf(b.w);
    *(us16x8*)(xb + idx) = v;
}

// ---------------------------------------------------------------- trans_wd (no LDS)
// Wd [I][H] fp32 -> Wdt [H][I] bf16 dequant. R2-proven. Thread owns one
// i-row's 64B h-chunk (4x dwordx4); writes 16 lane-coalesced 2B stores
// (128B/wave-instr). Grid 43 x 256 = 11008 blocks.
__global__ __launch_bounds__(256) void trans_wd(
    const float* __restrict__ wd, const float* __restrict__ sd, us16* __restrict__ wdt)
{
    const int t   = threadIdx.x;
    const int bid = blockIdx.x;
    const int bi  = bid % (I_DIM / 256);      // 43
    const int bh  = bid / (I_DIM / 256);      // 256
    const int i   = bi * 256 + t;
    const int h0  = bh * 16;
    const float s = sd[(i >> 7) * (H_DIM / 128) + (h0 >> 7)];
    const float* src = wd + (size_t)i * H_DIM + h0;
    float4 v0 = *(const float4*)(src + 0);
    float4 v1 = *(const float4*)(src + 4);
    float4 v2 = *(const float4*)(src + 8);
    float4 v3 = *(const float4*)(src + 12);
    us16 o[16];
    o[0]=f2bf(v0.x*s); o[1]=f2bf(v0.y*s); o[2]=f2bf(v0.z*s); o[3]=f2bf(v0.w*s);
    o[4]=f2bf(v1.x*s); o[5]=f2bf(v1.y*s); o[6]=f2bf(v1.z*s); o[7]=f2bf(v1.w*s);
    o[8]=f2bf(v2.x*s); o[9]=f2bf(v2.y*s); o[10]=f2bf(v2.z*s); o[11]=f2bf(v2.w*s);
    o[12]=f2bf(v3.x*s); o[13]=f2bf(v3.y*s); o[14]=f2bf(v3.z*s); o[15]=f2bf(v3.w*s);
    #pragma unroll
    for (int j = 0; j < 16; ++j)
        wdt[(size_t)(h0 + j) * I_DIM + i] = o[j];
}

// ---------------------------------------------------------------- gemm1 (fused gate+up)
// BM=128 BN=64 BK=64, grid 688 = 8 XCD x 86. Depth-1 register prefetch
// (depth-2 spilled: R1 WRITE_SIZE 14MB->1.46GB). XCD swizzle (R2-verified:
// FETCH 738->237 MB, 308->202us).
__global__ __launch_bounds__(256, 3) void gemm1_fused(
    const us16*  __restrict__ xb,
    const float* __restrict__ wg,
    const float* __restrict__ wu,
    const float* __restrict__ sgArr,
    const float* __restrict__ suArr,
    us16*        __restrict__ hbuf)
{
    __shared__ us16 As [128 * 72];    // stride 72: 16B-aligned, conflict-free frag reads
    __shared__ us16 Bgs[64 * 72];
    __shared__ us16 Bus[64 * 72];

    const int t    = threadIdx.x;
    const int bid  = blockIdx.x;              // 688 = 8 * 86
    const int wgid = (bid & 7) * 86 + (bid >> 3);   // XCD-contiguous
    const int bm   = wgid & 3;
    const int bn   = wgid >> 2;               // 0..171
    const int m0   = bm * 128, n0 = bn * 64;

    const int w = t >> 6, l = t & 63;
    const int q = l >> 4, r = l & 15;
    const int m_off = (w >> 1) * 64, n_off = (w & 1) * 32;

    // staging coordinates (fixed per thread)
    const int ar[4] = { t >> 3, (t + 256) >> 3, (t + 512) >> 3, (t + 768) >> 3 };
    const int ac    = (t & 7) * 8;                 // A: col in elems
    const int br[4] = { t >> 4, (t + 256) >> 4, (t + 512) >> 4, (t + 768) >> 4 };
    const int bc    = (t & 15) * 4;                // B: col in floats

    f32x4 accg[4][2], accu[4][2];
    #pragma unroll
    for (int m = 0; m < 4; ++m)
        #pragma unroll
        for (int n = 0; n < 2; ++n) {
            accg[m][n] = f32x4{0.f,0.f,0.f,0.f};
            accu[m][n] = f32x4{0.f,0.f,0.f,0.f};
        }

    us16x8 ab[4];
    float4 gb[4], ub[4];

    // prologue: prefetch iter 0
    {
        const int k0 = 0;
        #pragma unroll
        for (int p = 0; p < 4; ++p)
            ab[p] = *(const us16x8*)(xb + (size_t)(m0 + ar[p]) * H_DIM + k0 + ac);
        #pragma unroll
        for (int p = 0; p < 4; ++p) {
            gb[p] = *(const float4*)(wg + (size_t)(n0 + br[p]) * H_DIM + k0 + bc);
            ub[p] = *(const float4*)(wu + (size_t)(n0 + br[p]) * H_DIM + k0 + bc);
        }
    }

    for (int kt = 0; kt < H_DIM / 64; ++kt) {      // 64 iters
        const float sg = sgArr[(bn >> 1) * (H_DIM / 128) + (kt >> 1)];
        const float su = suArr[(bn >> 1) * (H_DIM / 128) + (kt >> 1)];

        __builtin_amdgcn_s_barrier();              // LDS WAR (reads of kt-1 done)

        // consume prefetched regs -> LDS
        #pragma unroll
        for (int p = 0; p < 4; ++p)
            *(us16x8*)(As + ar[p] * 72 + ac) = ab[p];
        #pragma unroll
        for (int p = 0; p < 4; ++p) {
            uint2 vg, vu;
            vg.x = pkbf(gb[p].x * sg, gb[p].y * sg);
            vg.y = pkbf(gb[p].z * sg, gb[p].w * sg);
            vu.x = pkbf(ub[p].x * su, ub[p].y * su);
            vu.y = pkbf(ub[p].z * su, ub[p].w * su);
            *(uint2*)(Bgs + br[p] * 72 + bc) = vg;
            *(uint2*)(Bus + br[p] * 72 + bc) = vu;
        }

        // prefetch next iter (wrap: last prefetch redundant but keeps counts uniform)
        {
            const int kn = ((kt + 1) & 63) * 64;
            #pragma unroll
            for (int p = 0; p < 4; ++p)
                ab[p] = *(const us16x8*)(xb + (size_t)(m0 + ar[p]) * H_DIM + kn + ac);
            #pragma unroll
            for (int p = 0; p < 4; ++p) {
                gb[p] = *(const float4*)(wg + (size_t)(n0 + br[p]) * H_DIM + kn + bc);
                ub[p] = *(const float4*)(wu + (size_t)(n0 + br[p]) * H_DIM + kn + bc);
            }
        }

        // pre-MFMA barrier WITHOUT vmcnt drain: prefetch stays in flight
        __builtin_amdgcn_s_waitcnt(0xC07F);        // lgkmcnt(0) only
        __builtin_amdgcn_s_barrier();

        #pragma unroll
        for (int ks = 0; ks < 2; ++ks) {
            us16x8 af[4], bg[2], bu[2];
            #pragma unroll
            for (int m = 0; m < 4; ++m)
                af[m] = *(const us16x8*)(As + (m_off + m * 16 + r) * 72 + ks * 32 + q * 8);
            #pragma unroll
            for (int n = 0; n < 2; ++n) {
                bg[n] = *(const us16x8*)(Bgs + (n_off + n * 16 + r) * 72 + ks * 32 + q * 8);
                bu[n] = *(const us16x8*)(Bus + (n_off + n * 16 + r) * 72 + ks * 32 + q * 8);
            }
            #pragma unroll
            for (int m = 0; m < 4; ++m)
                #pragma unroll
                for (int n = 0; n < 2; ++n) {
                    accg[m][n] = mfma16(af[m], bg[n], accg[m][n]);
                    accu[m][n] = mfma16(af[m], bu[n], accu[m][n]);
                }
        }
    }

    #pragma unroll
    for (int m = 0; m < 4; ++m)
        #pragma unroll
        for (int n = 0; n < 2; ++n)
            #pragma unroll
            for (int rr = 0; rr < 4; ++rr) {
                int grow = m0 + m_off + m * 16 + q * 4 + rr;
                int gcol = n0 + n_off + n * 16 + r;
                float g = accg[m][n][rr];
                float u = accu[m][n][rr];
                float hv = (g / (1.0f + __expf(-g))) * u;
                hbuf[(size_t)grow * I_DIM + gcol] = f2bf(hv);
            }
}

// ---------------------------------------------------------------- gemm2 split-K, pipelined
// 128x128 tile, BK=64, KSPLIT=4 -> 512 blocks = 2/CU. Structurally a port
// of gemm1's proven pipeline: register-staged prefetch of both bf16
// K-contiguous operands, LDS stride 72, no-vmcnt-drain pre-MFMA barrier
// (old version drained vmcnt(0) at every tile via global_load_lds +
// __syncthreads -> zero overlap). XCD swizzle as R2 (4 bm-blocks per
// (bn,bk) on one XCD -> wdt panel L2 reuse).
template <bool USE_PART>
__global__ __launch_bounds__(256, 2) void gemm2_splitk(
    const us16* __restrict__ hbuf,   // [T][I]
    const us16* __restrict__ wdt,    // [H][I]
    float*      __restrict__ outp)   // partials [KSPLIT][T][H] or out [T][H]
{
    __shared__ us16 As[128 * 72];
    __shared__ us16 Bs[128 * 72];

    const int t   = threadIdx.x;
    const int bid = blockIdx.x;          // 512 = 8 * 64
    const int xcd = bid & 7;             // XCD
    const int j   = bid >> 3;            // 0..63 within XCD
    const int bm  = j & 3;
    const int g   = xcd * 16 + (j >> 2); // 0..127
    const int bn  = g & 31;
    const int bk  = g >> 5;
    const int m0  = bm * 128, n0 = bn * 128;
    const int kbase = bk * (I_DIM / KSPLIT);   // 2752 per split

    const int w = t >> 6, l = t & 63;
    const int q = l >> 4, r = l & 15;
    const int m_off = (w >> 1) * 64, n_off = (w & 1) * 64;

    // staging coords (gemm1's A pattern, reused for both operands):
    // 128 rows x 64 elems, 8 threads/row, us16x8 each, 4 passes
    const int sr[4] = { t >> 3, (t >> 3) + 32, (t >> 3) + 64, (t >> 3) + 96 };
    const int sc    = (t & 7) * 8;

    f32x4 acc[4][4];
    #pragma unroll
    for (int m = 0; m < 4; ++m)
        #pragma unroll
        for (int n = 0; n < 4; ++n) acc[m][n] = f32x4{0.f,0.f,0.f,0.f};

    us16x8 aReg[4], bReg[4];

    // prologue: prefetch iter 0
    {
        const int k0 = kbase;
        #pragma unroll
        for (int p = 0; p < 4; ++p) {
            aReg[p] = *(const us16x8*)(hbuf + (size_t)(m0 + sr[p]) * I_DIM + k0 + sc);
            bReg[p] = *(const us16x8*)(wdt  + (size_t)(n0 + sr[p]) * I_DIM + k0 + sc);
        }
    }

    const int NT = (I_DIM / KSPLIT) / 64;          // 43
    for (int kt = 0; kt < NT; ++kt) {
        __builtin_amdgcn_s_barrier();              // LDS WAR (reads of kt-1 done)

        // consume prefetched regs -> LDS
        #pragma unroll
        for (int p = 0; p < 4; ++p) {
            *(us16x8*)(As + sr[p] * 72 + sc) = aReg[p];
            *(us16x8*)(Bs + sr[p] * 72 + sc) = bReg[p];
        }

        // prefetch next iter (wrap keeps counts uniform; last prefetch redundant)
        {
            int ktn = kt + 1; if (ktn == NT) ktn = 0;
            const int k0n = kbase + ktn * 64;
            #pragma unroll
            for (int p = 0; p < 4; ++p) {
                aReg[p] = *(const us16x8*)(hbuf + (size_t)(m0 + sr[p]) * I_DIM + k0n + sc);
                bReg[p] = *(const us16x8*)(wdt  + (size_t)(n0 + sr[p]) * I_DIM + k0n + sc);
            }
        }

        // pre-MFMA barrier WITHOUT vmcnt drain: prefetch stays in flight
        __builtin_amdgcn_s_waitcnt(0xC07F);        // lgkmcnt(0) only
        __builtin_amdgcn_s_barrier();

        #pragma unroll
        for (int ks = 0; ks < 2; ++ks) {
            us16x8 af[4], bfr[4];
            #pragma unroll
            for (int m = 0; m < 4; ++m)
                af[m] = *(const us16x8*)(As + (m_off + m * 16 + r) * 72 + ks * 32 + q * 8);
            #pragma unroll
            for (int n = 0; n < 4; ++n)
                bfr[n] = *(const us16x8*)(Bs + (n_off + n * 16 + r) * 72 + ks * 32 + q * 8);
            #pragma unroll
            for (int m = 0; m < 4; ++m)
                #pragma unroll
                for (int n = 0; n < 4; ++n)
                    acc[m][n] = mfma16(af[m], bfr[n], acc[m][n]);
        }
    }

    float* base = USE_PART ? outp + (size_t)bk * T_DIM * H_DIM : outp;
    #pragma unroll
    for (int m = 0; m < 4; ++m)
        #pragma unroll
        for (int n = 0; n < 4; ++n)
            #pragma unroll
            for (int rr = 0; rr < 4; ++rr) {
                int grow = m0 + m_off + m * 16 + q * 4 + rr;
                int gcol = n0 + n_off + n * 16 + r;
                if (USE_PART)
                    base[(size_t)grow * H_DIM + gcol] = acc[m][n][rr];
                else
                    atomicAdd(&base[(size_t)grow * H_DIM + gcol], acc[m][n][rr]);
            }
}

// ---------------------------------------------------------------- reduce partials
__global__ void reduce4_kernel(const float* __restrict__ part, float* __restrict__ out) {
    const size_t i = ((size_t)blockIdx.x * 256 + threadIdx.x) * 4;
    const size_t S = (size_t)T_DIM * H_DIM;
    float4 a = *(const float4*)(part + i);
    float4 b = *(const float4*)(part + S + i);
    float4 c = *(const float4*)(part + 2 * S + i);
    float4 d = *(const float4*)(part + 3 * S + i);
    float4 o;
    o.x = a.x + b.x + c.x + d.x;
    o.y = a.y + b.y + c.y + d.y;
    o.z = a.z + b.z + c.z + d.z;
    o.w = a.w + b.w + c.w + d.w;
    *(float4*)(out + i) = o;
}

// ---------------------------------------------------------------- launch
extern "C" void kernel_launch(void* const* d_in, const int* in_sizes, int n_in,
                              void* d_out, int out_size, void* d_ws, size_t ws_size,
                              hipStream_t stream) {
    const float* x  = (const float*)d_in[0];
    const float* wg = (const float*)d_in[1];
    const float* wu = (const float*)d_in[2];
    const float* wd = (const float*)d_in[3];
    const float* sg = (const float*)d_in[4];
    const float* su = (const float*)d_in[5];
    const float* sd = (const float*)d_in[6];
    float* out = (float*)d_out;

    const size_t xb_bytes   = (size_t)T_DIM * H_DIM * 2;           //  4.0 MB
    const size_t hb_bytes   = (size_t)T_DIM * I_DIM * 2;           // 11.3 MB
    const size_t wdt_bytes  = (size_t)H_DIM * I_DIM * 2;           // 90.2 MB
    const size_t part_bytes = (size_t)KSPLIT * T_DIM * H_DIM * 4;  // 33.6 MB

    us16*  xb   = (us16*)d_ws;
    us16*  hb   = (us16*)((char*)d_ws + xb_bytes);
    us16*  wdt  = (us16*)((char*)d_ws + xb_bytes + hb_bytes);
    float* part = (float*)((char*)d_ws + xb_bytes + hb_bytes + wdt_bytes);

    cvt_x_kernel<<<(T_DIM * H_DIM) / (256 * 8), 256, 0, stream>>>(x, xb);
    gemm1_fused<<<(I_DIM / 64) * (T_DIM / 128), 256, 0, stream>>>(xb, wg, wu, sg, su, hb);
    trans_wd<<<(I_DIM / 256) * (H_DIM / 16), 256, 0, stream>>>(wd, sd, wdt);

    if (ws_size >= xb_bytes + hb_bytes + wdt_bytes + part_bytes) {
        gemm2_splitk<true><<<(T_DIM / 128) * (H_DIM / 128) * KSPLIT, 256, 0, stream>>>(hb, wdt, part);
        reduce4_kernel<<<(T_DIM * H_DIM) / (256 * 4), 256, 0, stream>>>(part, out);
    } else {
        (void)hipMemsetAsync(out, 0, (size_t)T_DIM * H_DIM * sizeof(float), stream);
        gemm2_splitk<false><<<(T_DIM / 128) * (H_DIM / 128) * KSPLIT, 256, 0, stream>>>(hb, wdt, out);
    }
}

// Round 5
// 622.619 us; speedup vs baseline: 2.1063x; 1.0334x over previous
//
#include <hip/hip_runtime.h>
#include <hip/hip_bf16.h>
#include <cstdint>
#include <cstddef>

#define T_DIM 512
#define H_DIM 4096
#define I_DIM 11008
#define KSPLIT 4
// blocksize BS = 128

#define G1_BLOCKS ((I_DIM / 64) * (T_DIM / 128))   // 688
#define TW_BLOCKS ((I_DIM / 256) * (H_DIM / 16))   // 11008

typedef __bf16 bf16_t;
typedef bf16_t bf16x8 __attribute__((ext_vector_type(8)));
typedef float f32x4 __attribute__((ext_vector_type(4)));
typedef unsigned short us16;
typedef us16 us16x8 __attribute__((ext_vector_type(8)));
typedef us16 us16x4 __attribute__((ext_vector_type(4)));

// fp32 -> bf16 RTNE (scalar)
__device__ __forceinline__ us16 f2bf(float f) {
    union { float f; uint32_t u; } v; v.f = f;
    uint32_t u = v.u;
    return (us16)((u + 0x7FFFu + ((u >> 16) & 1u)) >> 16);
}

// packed fp32x2 -> bf16x2 dword via HW v_cvt_pk_bf16_f32 (RTNE)
__device__ __forceinline__ uint32_t pkbf(float a, float b) {
    __hip_bfloat162 h = __float22bfloat162_rn(make_float2(a, b));
    uint32_t u;
    __builtin_memcpy(&u, &h, 4);
    return u;
}

__device__ __forceinline__ f32x4 mfma16(us16x8 a, us16x8 b, f32x4 c) {
    return __builtin_amdgcn_mfma_f32_16x16x32_bf16(
        __builtin_bit_cast(bf16x8, a), __builtin_bit_cast(bf16x8, b), c, 0, 0, 0);
}

// ---------------------------------------------------------------- cvt_x
__global__ void cvt_x_kernel(const float* __restrict__ x, us16* __restrict__ xb) {
    int idx = (blockIdx.x * 256 + threadIdx.x) * 8;
    float4 a = *(const float4*)(x + idx);
    float4 b = *(const float4*)(x + idx + 4);
    us16x8 v;
    v[0] = f2bf(a.x); v[1] = f2bf(a.y); v[2] = f2bf(a.z); v[3] = f2bf(a.w);
    v[4] = f2bf(b.x); v[5] = f2bf(b.y); v[6] = f2bf(b.z); v[7] = f2bf(b.w);
    *(us16x8*)(xb + idx) = v;
}

// ---------------------------------------------------------------- gemm1 + trans_wd fat kernel
// Rationale (R4 post-mortem): gemm1 (latency-bound: 16% HBM, 20% MfmaUtil,
// 3 blocks/CU of 4 LDS-allowed) and trans_wd (request/latency-bound
// streaming, ~1.5 TB/s) are data-independent but were serialized on the
// stream: 195us + ~170us. Fat-merge: bids 0..687 run gemm1 (resident the
// whole kernel), bids 688.. run trans_wd, streaming through the spare
// ~1 block-slot/CU during gemm1's shadow. Both bodies are byte-identical
// to their R2/R4-proven standalone versions.
__global__ __launch_bounds__(256, 3) void gemm1_trans_fused(
    const us16*  __restrict__ xb,
    const float* __restrict__ wg,
    const float* __restrict__ wu,
    const float* __restrict__ sgArr,
    const float* __restrict__ suArr,
    us16*        __restrict__ hbuf,
    const float* __restrict__ wd,
    const float* __restrict__ sd,
    us16*        __restrict__ wdt)
{
    __shared__ us16 As [128 * 72];    // stride 72: 16B-aligned, conflict-free frag reads
    __shared__ us16 Bgs[64 * 72];
    __shared__ us16 Bus[64 * 72];

    const int t = threadIdx.x;

    if (blockIdx.x >= G1_BLOCKS) {
        // ---------------- trans_wd path (R2-proven body) ----------------
        const int bid = blockIdx.x - G1_BLOCKS;
        const int bi  = bid % (I_DIM / 256);      // 43
        const int bh  = bid / (I_DIM / 256);      // 256
        const int i   = bi * 256 + t;
        const int h0  = bh * 16;
        const float s = sd[(i >> 7) * (H_DIM / 128) + (h0 >> 7)];
        const float* src = wd + (size_t)i * H_DIM + h0;
        float4 v0 = *(const float4*)(src + 0);
        float4 v1 = *(const float4*)(src + 4);
        float4 v2 = *(const float4*)(src + 8);
        float4 v3 = *(const float4*)(src + 12);
        us16 o[16];
        o[0]=f2bf(v0.x*s); o[1]=f2bf(v0.y*s); o[2]=f2bf(v0.z*s); o[3]=f2bf(v0.w*s);
        o[4]=f2bf(v1.x*s); o[5]=f2bf(v1.y*s); o[6]=f2bf(v1.z*s); o[7]=f2bf(v1.w*s);
        o[8]=f2bf(v2.x*s); o[9]=f2bf(v2.y*s); o[10]=f2bf(v2.z*s); o[11]=f2bf(v2.w*s);
        o[12]=f2bf(v3.x*s); o[13]=f2bf(v3.y*s); o[14]=f2bf(v3.z*s); o[15]=f2bf(v3.w*s);
        #pragma unroll
        for (int jj = 0; jj < 16; ++jj)
            wdt[(size_t)(h0 + jj) * I_DIM + i] = o[jj];
        return;
    }

    // ---------------- gemm1 path (R2/R4-proven body) ----------------
    const int bid  = blockIdx.x;              // 0..687 = 8 XCD x 86
    const int wgid = (bid & 7) * 86 + (bid >> 3);   // XCD-contiguous
    const int bm   = wgid & 3;
    const int bn   = wgid >> 2;               // 0..171
    const int m0   = bm * 128, n0 = bn * 64;

    const int w = t >> 6, l = t & 63;
    const int q = l >> 4, r = l & 15;
    const int m_off = (w >> 1) * 64, n_off = (w & 1) * 32;

    // staging coordinates (fixed per thread)
    const int ar[4] = { t >> 3, (t + 256) >> 3, (t + 512) >> 3, (t + 768) >> 3 };
    const int ac    = (t & 7) * 8;                 // A: col in elems
    const int br[4] = { t >> 4, (t + 256) >> 4, (t + 512) >> 4, (t + 768) >> 4 };
    const int bc    = (t & 15) * 4;                // B: col in floats

    f32x4 accg[4][2], accu[4][2];
    #pragma unroll
    for (int m = 0; m < 4; ++m)
        #pragma unroll
        for (int n = 0; n < 2; ++n) {
            accg[m][n] = f32x4{0.f,0.f,0.f,0.f};
            accu[m][n] = f32x4{0.f,0.f,0.f,0.f};
        }

    us16x8 ab[4];
    float4 gb[4], ub[4];

    // prologue: prefetch iter 0
    {
        const int k0 = 0;
        #pragma unroll
        for (int p = 0; p < 4; ++p)
            ab[p] = *(const us16x8*)(xb + (size_t)(m0 + ar[p]) * H_DIM + k0 + ac);
        #pragma unroll
        for (int p = 0; p < 4; ++p) {
            gb[p] = *(const float4*)(wg + (size_t)(n0 + br[p]) * H_DIM + k0 + bc);
            ub[p] = *(const float4*)(wu + (size_t)(n0 + br[p]) * H_DIM + k0 + bc);
        }
    }

    for (int kt = 0; kt < H_DIM / 64; ++kt) {      // 64 iters
        const float sg = sgArr[(bn >> 1) * (H_DIM / 128) + (kt >> 1)];
        const float su = suArr[(bn >> 1) * (H_DIM / 128) + (kt >> 1)];

        __builtin_amdgcn_s_barrier();              // LDS WAR (reads of kt-1 done)

        // consume prefetched regs -> LDS
        #pragma unroll
        for (int p = 0; p < 4; ++p)
            *(us16x8*)(As + ar[p] * 72 + ac) = ab[p];
        #pragma unroll
        for (int p = 0; p < 4; ++p) {
            uint2 vg, vu;
            vg.x = pkbf(gb[p].x * sg, gb[p].y * sg);
            vg.y = pkbf(gb[p].z * sg, gb[p].w * sg);
            vu.x = pkbf(ub[p].x * su, ub[p].y * su);
            vu.y = pkbf(ub[p].z * su, ub[p].w * su);
            *(uint2*)(Bgs + br[p] * 72 + bc) = vg;
            *(uint2*)(Bus + br[p] * 72 + bc) = vu;
        }

        // prefetch next iter (wrap: last prefetch redundant but keeps counts uniform)
        {
            const int kn = ((kt + 1) & 63) * 64;
            #pragma unroll
            for (int p = 0; p < 4; ++p)
                ab[p] = *(const us16x8*)(xb + (size_t)(m0 + ar[p]) * H_DIM + kn + ac);
            #pragma unroll
            for (int p = 0; p < 4; ++p) {
                gb[p] = *(const float4*)(wg + (size_t)(n0 + br[p]) * H_DIM + kn + bc);
                ub[p] = *(const float4*)(wu + (size_t)(n0 + br[p]) * H_DIM + kn + bc);
            }
        }

        // pre-MFMA barrier WITHOUT vmcnt drain: prefetch stays in flight
        __builtin_amdgcn_s_waitcnt(0xC07F);        // lgkmcnt(0) only
        __builtin_amdgcn_s_barrier();

        #pragma unroll
        for (int ks = 0; ks < 2; ++ks) {
            us16x8 af[4], bg[2], bu[2];
            #pragma unroll
            for (int m = 0; m < 4; ++m)
                af[m] = *(const us16x8*)(As + (m_off + m * 16 + r) * 72 + ks * 32 + q * 8);
            #pragma unroll
            for (int n = 0; n < 2; ++n) {
                bg[n] = *(const us16x8*)(Bgs + (n_off + n * 16 + r) * 72 + ks * 32 + q * 8);
                bu[n] = *(const us16x8*)(Bus + (n_off + n * 16 + r) * 72 + ks * 32 + q * 8);
            }
            #pragma unroll
            for (int m = 0; m < 4; ++m)
                #pragma unroll
                for (int n = 0; n < 2; ++n) {
                    accg[m][n] = mfma16(af[m], bg[n], accg[m][n]);
                    accu[m][n] = mfma16(af[m], bu[n], accu[m][n]);
                }
        }
    }

    #pragma unroll
    for (int m = 0; m < 4; ++m)
        #pragma unroll
        for (int n = 0; n < 2; ++n)
            #pragma unroll
            for (int rr = 0; rr < 4; ++rr) {
                int grow = m0 + m_off + m * 16 + q * 4 + rr;
                int gcol = n0 + n_off + n * 16 + r;
                float g = accg[m][n][rr];
                float u = accu[m][n][rr];
                float hv = (g / (1.0f + __expf(-g))) * u;
                hbuf[(size_t)grow * I_DIM + gcol] = f2bf(hv);
            }
}

// ---------------------------------------------------------------- gemm2 split-K, pipelined
// 128x128 tile, BK=64, KSPLIT=4 -> 512 blocks = 2/CU. gemm1-style pipeline
// (R4-proven): register-staged prefetch of both bf16 K-contiguous operands,
// LDS stride 72, no-vmcnt-drain pre-MFMA barrier. XCD swizzle (4 bm-blocks
// per (bn,bk) on one XCD -> wdt panel L2 reuse).
template <bool USE_PART>
__global__ __launch_bounds__(256, 2) void gemm2_splitk(
    const us16* __restrict__ hbuf,   // [T][I]
    const us16* __restrict__ wdt,    // [H][I]
    float*      __restrict__ outp)   // partials [KSPLIT][T][H] or out [T][H]
{
    __shared__ us16 As[128 * 72];
    __shared__ us16 Bs[128 * 72];

    const int t   = threadIdx.x;
    const int bid = blockIdx.x;          // 512 = 8 * 64
    const int xcd = bid & 7;             // XCD
    const int j   = bid >> 3;            // 0..63 within XCD
    const int bm  = j & 3;
    const int g   = xcd * 16 + (j >> 2); // 0..127
    const int bn  = g & 31;
    const int bk  = g >> 5;
    const int m0  = bm * 128, n0 = bn * 128;
    const int kbase = bk * (I_DIM / KSPLIT);   // 2752 per split

    const int w = t >> 6, l = t & 63;
    const int q = l >> 4, r = l & 15;
    const int m_off = (w >> 1) * 64, n_off = (w & 1) * 64;

    // staging coords: 128 rows x 64 elems, 8 threads/row, us16x8 each, 4 passes
    const int sr[4] = { t >> 3, (t >> 3) + 32, (t >> 3) + 64, (t >> 3) + 96 };
    const int sc    = (t & 7) * 8;

    f32x4 acc[4][4];
    #pragma unroll
    for (int m = 0; m < 4; ++m)
        #pragma unroll
        for (int n = 0; n < 4; ++n) acc[m][n] = f32x4{0.f,0.f,0.f,0.f};

    us16x8 aReg[4], bReg[4];

    // prologue: prefetch iter 0
    {
        const int k0 = kbase;
        #pragma unroll
        for (int p = 0; p < 4; ++p) {
            aReg[p] = *(const us16x8*)(hbuf + (size_t)(m0 + sr[p]) * I_DIM + k0 + sc);
            bReg[p] = *(const us16x8*)(wdt  + (size_t)(n0 + sr[p]) * I_DIM + k0 + sc);
        }
    }

    const int NT = (I_DIM / KSPLIT) / 64;          // 43
    for (int kt = 0; kt < NT; ++kt) {
        __builtin_amdgcn_s_barrier();              // LDS WAR (reads of kt-1 done)

        // consume prefetched regs -> LDS
        #pragma unroll
        for (int p = 0; p < 4; ++p) {
            *(us16x8*)(As + sr[p] * 72 + sc) = aReg[p];
            *(us16x8*)(Bs + sr[p] * 72 + sc) = bReg[p];
        }

        // prefetch next iter (wrap keeps counts uniform; last prefetch redundant)
        {
            int ktn = kt + 1; if (ktn == NT) ktn = 0;
            const int k0n = kbase + ktn * 64;
            #pragma unroll
            for (int p = 0; p < 4; ++p) {
                aReg[p] = *(const us16x8*)(hbuf + (size_t)(m0 + sr[p]) * I_DIM + k0n + sc);
                bReg[p] = *(const us16x8*)(wdt  + (size_t)(n0 + sr[p]) * I_DIM + k0n + sc);
            }
        }

        // pre-MFMA barrier WITHOUT vmcnt drain: prefetch stays in flight
        __builtin_amdgcn_s_waitcnt(0xC07F);        // lgkmcnt(0) only
        __builtin_amdgcn_s_barrier();

        #pragma unroll
        for (int ks = 0; ks < 2; ++ks) {
            us16x8 af[4], bfr[4];
            #pragma unroll
            for (int m = 0; m < 4; ++m)
                af[m] = *(const us16x8*)(As + (m_off + m * 16 + r) * 72 + ks * 32 + q * 8);
            #pragma unroll
            for (int n = 0; n < 4; ++n)
                bfr[n] = *(const us16x8*)(Bs + (n_off + n * 16 + r) * 72 + ks * 32 + q * 8);
            #pragma unroll
            for (int m = 0; m < 4; ++m)
                #pragma unroll
                for (int n = 0; n < 4; ++n)
                    acc[m][n] = mfma16(af[m], bfr[n], acc[m][n]);
        }
    }

    float* base = USE_PART ? outp + (size_t)bk * T_DIM * H_DIM : outp;
    #pragma unroll
    for (int m = 0; m < 4; ++m)
        #pragma unroll
        for (int n = 0; n < 4; ++n)
            #pragma unroll
            for (int rr = 0; rr < 4; ++rr) {
                int grow = m0 + m_off + m * 16 + q * 4 + rr;
                int gcol = n0 + n_off + n * 16 + r;
                if (USE_PART)
                    base[(size_t)grow * H_DIM + gcol] = acc[m][n][rr];
                else
                    atomicAdd(&base[(size_t)grow * H_DIM + gcol], acc[m][n][rr]);
            }
}

// ---------------------------------------------------------------- reduce partials
__global__ void reduce4_kernel(const float* __restrict__ part, float* __restrict__ out) {
    const size_t i = ((size_t)blockIdx.x * 256 + threadIdx.x) * 4;
    const size_t S = (size_t)T_DIM * H_DIM;
    float4 a = *(const float4*)(part + i);
    float4 b = *(const float4*)(part + S + i);
    float4 c = *(const float4*)(part + 2 * S + i);
    float4 d = *(const float4*)(part + 3 * S + i);
    float4 o;
    o.x = a.x + b.x + c.x + d.x;
    o.y = a.y + b.y + c.y + d.y;
    o.z = a.z + b.z + c.z + d.z;
    o.w = a.w + b.w + c.w + d.w;
    *(float4*)(out + i) = o;
}

// ---------------------------------------------------------------- launch
extern "C" void kernel_launch(void* const* d_in, const int* in_sizes, int n_in,
                              void* d_out, int out_size, void* d_ws, size_t ws_size,
                              hipStream_t stream) {
    const float* x  = (const float*)d_in[0];
    const float* wg = (const float*)d_in[1];
    const float* wu = (const float*)d_in[2];
    const float* wd = (const float*)d_in[3];
    const float* sg = (const float*)d_in[4];
    const float* su = (const float*)d_in[5];
    const float* sd = (const float*)d_in[6];
    float* out = (float*)d_out;

    const size_t xb_bytes   = (size_t)T_DIM * H_DIM * 2;           //  4.0 MB
    const size_t hb_bytes   = (size_t)T_DIM * I_DIM * 2;           // 11.3 MB
    const size_t wdt_bytes  = (size_t)H_DIM * I_DIM * 2;           // 90.2 MB
    const size_t part_bytes = (size_t)KSPLIT * T_DIM * H_DIM * 4;  // 33.6 MB

    us16*  xb   = (us16*)d_ws;
    us16*  hb   = (us16*)((char*)d_ws + xb_bytes);
    us16*  wdt  = (us16*)((char*)d_ws + xb_bytes + hb_bytes);
    float* part = (float*)((char*)d_ws + xb_bytes + hb_bytes + wdt_bytes);

    cvt_x_kernel<<<(T_DIM * H_DIM) / (256 * 8), 256, 0, stream>>>(x, xb);
    gemm1_trans_fused<<<G1_BLOCKS + TW_BLOCKS, 256, 0, stream>>>(
        xb, wg, wu, sg, su, hb, wd, sd, wdt);

    if (ws_size >= xb_bytes + hb_bytes + wdt_bytes + part_bytes) {
        gemm2_splitk<true><<<(T_DIM / 128) * (H_DIM / 128) * KSPLIT, 256, 0, stream>>>(hb, wdt, part);
        reduce4_kernel<<<(T_DIM * H_DIM) / (256 * 4), 256, 0, stream>>>(part, out);
    } else {
        (void)hipMemsetAsync(out, 0, (size_t)T_DIM * H_DIM * sizeof(float), stream);
        gemm2_splitk<false><<<(T_DIM / 128) * (H_DIM / 128) * KSPLIT, 256, 0, stream>>>(hb, wdt, out);
    }
}